// Round 6
// baseline (386.835 us; speedup 1.0000x reference)
//
#include <hip/hip_runtime.h>

typedef unsigned int uint;
typedef unsigned short ushort;

using bf16x8 = __attribute__((ext_vector_type(8))) short;
using f32x4  = __attribute__((ext_vector_type(4))) float;
using u32x4  = __attribute__((ext_vector_type(4))) uint;

__device__ __forceinline__ float lrelu(float v) { return v > 0.f ? v : 0.01f * v; }
__device__ __forceinline__ float b2f(ushort u) { return __uint_as_float((uint)u << 16); }
__device__ __forceinline__ ushort f2b(float f) {
  uint u = __float_as_uint(f);
  u += 0x7fffu + ((u >> 16) & 1u);   // round-to-nearest-even
  return (ushort)(u >> 16);
}

#define CSR_B 256          // blocks in coarse passes
#define BKT_SHIFT 10       // 1024 dst nodes per bucket
#define MAX_NB 64          // max buckets (N <= 65536)

// y buffers are CHANNEL-CHUNKED into 2 chunks of 64 ch: y[chunk][node][64].
// Evidence ledger:
//  R2: nontemporal hints break producer->consumer caching (-21%).
//  R3: LPT perm = 116us atomic contention; imbalance not the issue.
//  R4: 8-wide gather batching (MLP) worth only ~2%.
//  R5: 64B->128B rows + halved request count + broken L2 chunk residency:
//      NEUTRAL. => agg cost tracks total gather BYTES at ~5 TB/s, invariant
//      to caching/balance/MLP. Only levers left: fewer bytes or overlap.
//  R6: fuse the 3rd agg of each layer INTO the MODE-1 GEMM: gather S*y2 into
//      LDS per 64-row block (rows are consumed exactly once, in block order).
//      Kills y3 write+read (25.6MB/layer) + 1 launch/flush per layer, and
//      overlaps gather with MFMA across co-resident blocks.

// ---------------------------------------------------------------------------
// MFMA GEMM: C[N,128] = A[N,K] @ W[K,128] + bias, bf16 in / fp32 acc.
// A given as chunked y-buffer pointers (K = 128*buffers), or — when F32A=1 —
// read directly from fp32 Xf[N][128] with in-register bf16 cast.
// When FUSE=1 (MODE 1, K=512): A chunks for K in [384,512) are computed on
// the fly as S*y2 (gather-sum over CSR rows) into LDS Ss, replacing the y3
// buffer entirely. A2 must point at y2; rowp/esrc give the CSR.
// Wt pre-transposed: Wt[n][k] bf16.
// MODE 0: h = lrelu(acc+b); yout = bf16(lrelu(h))           (readin)
// MODE 1: h += acc+b; if yout: yout = bf16(act? lrelu(h):h) (layer taps)
//         store_h=0 skips the h writeback (last layer: h is dead after y0)
// MODE 2: h = acc+b                                          (readout)
// ---------------------------------------------------------------------------
template <int MODE, int K, int F32A, int FUSE>
__global__ __launch_bounds__(256) void gemm_mfma(
    const ushort* __restrict__ A0, const ushort* __restrict__ A1,
    const ushort* __restrict__ A2, const ushort* __restrict__ A3,
    const float* __restrict__ Xf,
    const ushort* __restrict__ Wt, const float* __restrict__ bias,
    const int* __restrict__ rowp, const ushort* __restrict__ esrc,
    float* __restrict__ h, ushort* __restrict__ yout, int do_act, int store_h,
    int N) {
  __shared__ ushort As[64][40];    // [m][k], stride 40 (16B-aligned, 2-way-free banks)
  __shared__ ushort Bs[128][40];   // [n][k]
  __shared__ ushort Ss[FUSE ? 64 : 1][136];  // fused S*y2 tile (64 rows x 128 ch)
  const int tid = threadIdx.x;
  const int lane = tid & 63;
  const int wave = tid >> 6;
  const int g = lane >> 4;         // k-quad
  const int mr = lane & 15;
  const int wr = wave >> 1;        // row half
  const int wc = wave & 1;         // col half
  const int row0 = blockIdx.x * 64;

  const ushort* Ap[4] = {A0, A1, A2, A3};

  if constexpr (FUSE) {
    // Gather phase: Ss[m][c] = bf16( sum_{e in row} y2[src(e)][c] ), c=0..127.
    // 16 lanes per row: lane16>>3 = chunk, (lane16&7)*8 = channel offset.
    const int lane16 = tid & 15;
    const int chunk = lane16 >> 3;
    const ushort* yb = A2 + (size_t)chunk * N * 64 + (lane16 & 7) * 8;
#pragma unroll
    for (int p = 0; p < 4; p++) {
      int m = (tid >> 4) + p * 16;
      int r = row0 + m;
      if (r >= N) r = N - 1;
      int beg = rowp[r], end = rowp[r + 1];
      float s[8] = {0.f, 0.f, 0.f, 0.f, 0.f, 0.f, 0.f, 0.f};
      int j = beg;
      for (; j + 4 <= end; j += 4) {
        int i0 = esrc[j], i1 = esrc[j + 1], i2 = esrc[j + 2], i3 = esrc[j + 3];
        union { u32x4 v; ushort u[8]; } w0, w1, w2, w3;
        w0.v = *(const u32x4*)(yb + (size_t)i0 * 64);
        w1.v = *(const u32x4*)(yb + (size_t)i1 * 64);
        w2.v = *(const u32x4*)(yb + (size_t)i2 * 64);
        w3.v = *(const u32x4*)(yb + (size_t)i3 * 64);
#pragma unroll
        for (int e = 0; e < 8; e++)
          s[e] += (b2f(w0.u[e]) + b2f(w1.u[e])) + (b2f(w2.u[e]) + b2f(w3.u[e]));
      }
      for (; j < end; j++) {
        int sn = esrc[j];
        union { u32x4 v; ushort u[8]; } w;
        w.v = *(const u32x4*)(yb + (size_t)sn * 64);
#pragma unroll
        for (int e = 0; e < 8; e++) s[e] += b2f(w.u[e]);
      }
      union { u32x4 v; ushort u[8]; } o;
#pragma unroll
      for (int e = 0; e < 8; e++) o.u[e] = f2b(s[e]);
      *(u32x4*)&Ss[m][lane16 * 8] = o.v;
    }
    __syncthreads();
  }

  f32x4 acc[2][4];
#pragma unroll
  for (int i = 0; i < 2; i++)
#pragma unroll
    for (int j = 0; j < 4; j++) acc[i][j] = (f32x4){0.f, 0.f, 0.f, 0.f};

#pragma unroll 4
  for (int kc = 0; kc < K; kc += 32) {
    if (!FUSE || kc < 384) {  // stage A: 64 rows x 32 k (16B of bf16 per thread)
      int m = tid >> 2, q = tid & 3;
      int r = row0 + m;
      if (r >= N) r = N - 1;
      if constexpr (F32A) {
        const float* xp = Xf + (size_t)r * 128 + kc + q * 8;
        f32x4 xa = *(const f32x4*)xp;
        f32x4 xb = *(const f32x4*)(xp + 4);
        union { u32x4 v; ushort u[8]; } o;
        o.u[0] = f2b(xa[0]); o.u[1] = f2b(xa[1]);
        o.u[2] = f2b(xa[2]); o.u[3] = f2b(xa[3]);
        o.u[4] = f2b(xb[0]); o.u[5] = f2b(xb[1]);
        o.u[6] = f2b(xb[2]); o.u[7] = f2b(xb[3]);
        *(u32x4*)&As[m][q * 8] = o.v;
      } else {
        int kg = kc + q * 8;
        // buffer = kg>>7 (128 ch per y buffer); chunk = (kg>>6)&1 (64-ch chunks)
        const ushort* ap = Ap[kg >> 7] + ((size_t)((kg >> 6) & 1)) * N * 64 +
                           (size_t)r * 64 + (kg & 63);
        *(u32x4*)&As[m][q * 8] = *(const u32x4*)ap;
      }
    }
#pragma unroll
    for (int t = 0; t < 2; t++) {  // stage B: 128 n x 32 k
      int slot = tid + t * 256;
      int n = slot >> 2, q = slot & 3;
      *(u32x4*)&Bs[n][q * 8] = *(const u32x4*)(Wt + (size_t)n * K + kc + q * 8);
    }
    __syncthreads();
    bf16x8 af[2], bf[4];
    if (FUSE && kc >= 384) {
#pragma unroll
      for (int rt = 0; rt < 2; rt++)
        af[rt] = *(bf16x8*)&Ss[wr * 32 + rt * 16 + mr][(kc - 384) + g * 8];
    } else {
#pragma unroll
      for (int rt = 0; rt < 2; rt++)
        af[rt] = *(bf16x8*)&As[wr * 32 + rt * 16 + mr][g * 8];
    }
#pragma unroll
    for (int ct = 0; ct < 4; ct++) bf[ct] = *(bf16x8*)&Bs[wc * 64 + ct * 16 + mr][g * 8];
#pragma unroll
    for (int rt = 0; rt < 2; rt++)
#pragma unroll
      for (int ct = 0; ct < 4; ct++)
        acc[rt][ct] = __builtin_amdgcn_mfma_f32_16x16x32_bf16(af[rt], bf[ct], acc[rt][ct], 0, 0, 0);
    __syncthreads();
  }

  // epilogue: C/D layout col=lane&15, row=(lane>>4)*4+reg
#pragma unroll
  for (int rt = 0; rt < 2; rt++) {
#pragma unroll
    for (int i = 0; i < 4; i++) {
      int R = row0 + wr * 32 + rt * 16 + g * 4 + i;
      if (R >= N) continue;
#pragma unroll
      for (int ct = 0; ct < 4; ct++) {
        int c = wc * 64 + ct * 16 + mr;       // chunk = c>>6, within = c&63
        float v = acc[rt][ct][i] + bias[c];
        size_t o = (size_t)R * 128 + c;
        size_t oy = (size_t)(c >> 6) * N * 64 + (size_t)R * 64 + (c & 63);
        if (MODE == 0) {
          float hv = lrelu(v);
          h[o] = hv;
          yout[oy] = f2b(lrelu(hv));
        } else if (MODE == 1) {
          float hv = h[o] + v;
          if (store_h) h[o] = hv;
          if (yout) yout[oy] = f2b(do_act ? lrelu(hv) : hv);
        } else {
          h[o] = v;
        }
      }
    }
  }
}

// ---------------- bf16 aggregation, chunked: out[c][n] = sum y[c][src] -------
// chunk = blockIdx&1. 8 lanes x 16B (8 bf16) per node -> one 128 B line per
// lane-octet. 32 nodes per block. 8-wide gather batches.
__global__ __launch_bounds__(256) void agg_bf16(const ushort* __restrict__ yin,
                                                ushort* __restrict__ yout,
                                                const int* __restrict__ rowp,
                                                const ushort* __restrict__ esrc, int N) {
  int t = threadIdx.x;
  int chunk = blockIdx.x & 1;
  int node = (blockIdx.x >> 1) * 32 + (t >> 3);
  if (node >= N) return;
  int lane = t & 7;
  const ushort* yb = yin + (size_t)chunk * N * 64 + lane * 8;
  int beg = rowp[node], end = rowp[node + 1];
  float s[8] = {0.f, 0.f, 0.f, 0.f, 0.f, 0.f, 0.f, 0.f};
  int j = beg;
  for (; j + 8 <= end; j += 8) {
    int is[8];
#pragma unroll
    for (int e = 0; e < 8; e++) is[e] = esrc[j + e];
    u32x4 w[8];
#pragma unroll
    for (int e = 0; e < 8; e++) w[e] = *(const u32x4*)(yb + (size_t)is[e] * 64);
#pragma unroll
    for (int e = 0; e < 8; e++) {
      union { u32x4 v; ushort u[8]; } q;
      q.v = w[e];
#pragma unroll
      for (int c = 0; c < 8; c++) s[c] += b2f(q.u[c]);
    }
  }
  if (j + 4 <= end) {
    int is[4];
#pragma unroll
    for (int e = 0; e < 4; e++) is[e] = esrc[j + e];
    u32x4 w[4];
#pragma unroll
    for (int e = 0; e < 4; e++) w[e] = *(const u32x4*)(yb + (size_t)is[e] * 64);
#pragma unroll
    for (int e = 0; e < 4; e++) {
      union { u32x4 v; ushort u[8]; } q;
      q.v = w[e];
#pragma unroll
      for (int c = 0; c < 8; c++) s[c] += b2f(q.u[c]);
    }
    j += 4;
  }
  for (; j < end; j++) {
    int sn = esrc[j];
    union { u32x4 v; ushort u[8]; } w;
    w.v = *(const u32x4*)(yb + (size_t)sn * 64);
#pragma unroll
    for (int e = 0; e < 8; e++) s[e] += b2f(w.u[e]);
  }
  union { u32x4 v; ushort u[8]; } o;
#pragma unroll
  for (int e = 0; e < 8; e++) o.u[e] = f2b(s[e]);
  *(u32x4*)(yout + (size_t)chunk * N * 64 + (size_t)node * 64 + lane * 8) = o.v;
}

// ---------------- weight prep: cast + transpose + bias sums ------------------
__global__ __launch_bounds__(256) void prep_k(const float* __restrict__ w_in,
                                              const float* __restrict__ w_out,
                                              const float* __restrict__ taps_w,
                                              const float* __restrict__ taps_b,
                                              ushort* __restrict__ Wt_in,
                                              ushort* __restrict__ Wt_out,
                                              ushort* __restrict__ Wt_l0,
                                              ushort* __restrict__ Wt_l1,
                                              float* __restrict__ bsum) {
  int gid = blockIdx.x * 256 + threadIdx.x;
  if (gid < 16384) {
    int n = gid >> 7, k = gid & 127;
    Wt_in[gid] = f2b(w_in[k * 128 + n]);
  } else if (gid < 32768) {
    int i = gid - 16384;
    int n = i >> 7, k = i & 127;
    Wt_out[i] = f2b(w_out[k * 128 + n]);
  } else if (gid < 98304) {
    int i = gid - 32768;
    int n = i >> 9, k = i & 511;
    Wt_l0[i] = f2b(taps_w[(size_t)k * 128 + n]);
  } else if (gid < 163840) {
    int i = gid - 98304;
    int n = i >> 9, k = i & 511;
    Wt_l1[i] = f2b(taps_w[(size_t)(512 + k) * 128 + n]);
  } else if (gid < 164096) {
    int i = gid - 163840;
    int l = i >> 7, n = i & 127;
    float s = 0.f;
    for (int k = 0; k < 4; k++) s += taps_b[l * 512 + k * 128 + n];
    bsum[i] = s;
  }
}

// ---------------- CSR build: 2-level binned counting sort --------------------
__global__ __launch_bounds__(256) void chist_k(const int* __restrict__ dst,
                                               int* __restrict__ H, int E, int NB) {
  __shared__ int hh[MAX_NB];
  if (threadIdx.x < NB) hh[threadIdx.x] = 0;
  __syncthreads();
  int chunk = (E + gridDim.x - 1) / gridDim.x;
  int beg = blockIdx.x * chunk, end = min(E, beg + chunk);
  for (int e = beg + threadIdx.x; e < end; e += 256)
    atomicAdd(&hh[dst[e] >> BKT_SHIFT], 1);
  __syncthreads();
  if (threadIdx.x < NB) H[threadIdx.x * gridDim.x + blockIdx.x] = hh[threadIdx.x];
}

__global__ __launch_bounds__(256) void cscan_k(int* __restrict__ H, int M) {
  __shared__ int sm[256];
  int per = (M + 255) / 256;
  int b0 = threadIdx.x * per;
  int hi = min(M, b0 + per);
  int sum = 0;
  for (int i = b0; i < hi; i++) sum += H[i];
  sm[threadIdx.x] = sum;
  __syncthreads();
  int x = sum;
  for (int off = 1; off < 256; off <<= 1) {
    int tt = (threadIdx.x >= off) ? sm[threadIdx.x - off] : 0;
    __syncthreads();
    x += tt;
    sm[threadIdx.x] = x;
    __syncthreads();
  }
  int run = x - sum;  // exclusive
  for (int i = b0; i < hi; i++) {
    int v = H[i];
    H[i] = run;
    run += v;
  }
}

__global__ __launch_bounds__(256) void cscatter_k(const int* __restrict__ src,
                                                  const int* __restrict__ dst,
                                                  const int* __restrict__ H,
                                                  uint* __restrict__ packed,
                                                  int E, int NB) {
  __shared__ int cur[MAX_NB];
  int chunk = (E + gridDim.x - 1) / gridDim.x;
  int beg = blockIdx.x * chunk, end = min(E, beg + chunk);
  if (threadIdx.x < NB) cur[threadIdx.x] = H[threadIdx.x * gridDim.x + blockIdx.x];
  __syncthreads();
  for (int e = beg + threadIdx.x; e < end; e += 256) {
    int d = dst[e];
    int pos = atomicAdd(&cur[d >> BKT_SHIFT], 1);
    packed[pos] = ((uint)d << 16) | (uint)src[e];
  }
}

__global__ __launch_bounds__(256) void fsort_k(const uint* __restrict__ packed,
                                               const int* __restrict__ H,
                                               ushort* __restrict__ esrc,
                                               int* __restrict__ rowp,
                                               int N, int E, int NB) {
  __shared__ int hist[1 << BKT_SHIFT];
  __shared__ int cur[1 << BKT_SHIFT];
  __shared__ int sm[256];
  const int bkt = blockIdx.x;
  const int base = bkt << BKT_SHIFT;
  const int nb_nodes = min(1 << BKT_SHIFT, N - base);
  const int start = H[bkt * CSR_B];
  const int end = (bkt == NB - 1) ? E : H[(bkt + 1) * CSR_B];

  for (int i = threadIdx.x; i < (1 << BKT_SHIFT); i += 256) hist[i] = 0;
  __syncthreads();
  for (int e = start + threadIdx.x; e < end; e += 256)
    atomicAdd(&hist[(packed[e] >> 16) - base], 1);
  __syncthreads();

  int t4 = threadIdx.x * 4;
  int l0 = hist[t4], l1 = hist[t4 + 1], l2 = hist[t4 + 2], l3 = hist[t4 + 3];
  int ssum = l0 + l1 + l2 + l3;
  sm[threadIdx.x] = ssum;
  __syncthreads();
  int x = ssum;
  for (int off = 1; off < 256; off <<= 1) {
    int tt = (threadIdx.x >= off) ? sm[threadIdx.x - off] : 0;
    __syncthreads();
    x += tt;
    sm[threadIdx.x] = x;
    __syncthreads();
  }
  int c0 = start + x - ssum;
  int c1 = c0 + l0, c2 = c1 + l1, c3 = c2 + l2;
  cur[t4] = c0; cur[t4 + 1] = c1; cur[t4 + 2] = c2; cur[t4 + 3] = c3;
  if (t4 + 0 < nb_nodes) rowp[base + t4 + 0] = c0;
  if (t4 + 1 < nb_nodes) rowp[base + t4 + 1] = c1;
  if (t4 + 2 < nb_nodes) rowp[base + t4 + 2] = c2;
  if (t4 + 3 < nb_nodes) rowp[base + t4 + 3] = c3;
  __syncthreads();

  for (int e = start + threadIdx.x; e < end; e += 256) {
    uint p = packed[e];
    int pos = atomicAdd(&cur[(p >> 16) - base], 1);
    esrc[pos] = (ushort)(p & 0xffffu);
  }
  if (bkt == 0 && threadIdx.x == 0) rowp[N] = E;
}

// ---------------------------------------------------------------------------
extern "C" void kernel_launch(void* const* d_in, const int* in_sizes, int n_in,
                              void* d_out, int out_size, void* d_ws, size_t ws_size,
                              hipStream_t stream) {
  const float* x      = (const float*)d_in[0];
  const int*   ei     = (const int*)d_in[1];
  const float* w_in   = (const float*)d_in[2];
  const float* b_in   = (const float*)d_in[3];
  const float* taps_w = (const float*)d_in[4];
  const float* taps_b = (const float*)d_in[5];
  const float* w_out  = (const float*)d_in[6];
  const float* b_out  = (const float*)d_in[7];

  const int N = in_sizes[0] / 128;
  const int E = in_sizes[1] / 2;
  const int* src = ei;
  const int* dst = ei + E;
  const int NB = (N + (1 << BKT_SHIFT) - 1) >> BKT_SHIFT;

  // h (fp32) lives in d_out until the readout GEMM overwrites it.
  float* h = (float*)d_out;

  // workspace (~57 MB)
  const size_t yelem = (size_t)N * 128;
  ushort* y0 = (ushort*)d_ws;
  ushort* y1 = y0 + yelem;
  ushort* y2 = y1 + yelem;
  ushort* y3 = y2 + yelem;                 // unused since R6 (kept for layout)
  ushort* Wt_in  = y3 + yelem;             // 128*128
  ushort* Wt_out = Wt_in + 128 * 128;      // 128*128
  ushort* Wt_l0  = Wt_out + 128 * 128;     // 128*512
  ushort* Wt_l1  = Wt_l0 + 128 * 512;      // 128*512
  float*  bsum   = (float*)(Wt_l1 + 128 * 512);   // 256
  int*    rowp   = (int*)(bsum + 256);     // N+1
  int*    H      = rowp + (N + 1);         // NB*CSR_B
  uint*   packed = (uint*)(H + MAX_NB * CSR_B);   // E
  ushort* esrc   = (ushort*)(packed + E);  // E

  const int gemmB = (N + 63) / 64;
  const int aggB  = ((N + 31) / 32) * 2;   // node-blocks x 2 chunks

  // ---- CSR build (binned counting sort) ----
  chist_k<<<CSR_B, 256, 0, stream>>>(dst, H, E, NB);
  cscan_k<<<1, 256, 0, stream>>>(H, NB * CSR_B);
  cscatter_k<<<CSR_B, 256, 0, stream>>>(src, dst, H, packed, E, NB);
  fsort_k<<<NB, 256, 0, stream>>>(packed, H, esrc, rowp, N, E, NB);

  // ---- weight prep ----
  prep_k<<<641, 256, 0, stream>>>(w_in, w_out, taps_w, taps_b,
                                  Wt_in, Wt_out, Wt_l0, Wt_l1, bsum);

  // ---- readin: h = lrelu(x@Win+b); y0 = bf16(lrelu(h)); x cast fused ----
  gemm_mfma<0, 128, 1, 0><<<gemmB, 256, 0, stream>>>(
      nullptr, nullptr, nullptr, nullptr, x, Wt_in, b_in, nullptr, nullptr,
      h, y0, 0, 1, N);

  // ---- 2 residual graph-filter layers; 3rd tap agg fused into the GEMM ----
  for (int l = 0; l < 2; l++) {
    const ushort* Wt_l = (l == 0) ? Wt_l0 : Wt_l1;
    agg_bf16<<<aggB, 256, 0, stream>>>(y0, y1, rowp, esrc, N);
    agg_bf16<<<aggB, 256, 0, stream>>>(y1, y2, rowp, esrc, N);
    gemm_mfma<1, 512, 0, 1><<<gemmB, 256, 0, stream>>>(
        y0, y1, y2, y2, nullptr, Wt_l, bsum + l * 128, rowp, esrc, h, y0,
        (l == 0) ? 1 : 0, (l == 0) ? 1 : 0, N);
  }

  // ---- readout: d_out = h @ Wout + bout (reads y0 = bf16(h)) ----
  gemm_mfma<2, 128, 0, 0><<<gemmB, 256, 0, stream>>>(
      y0, y0, y0, y0, nullptr, Wt_out, b_out, nullptr, nullptr,
      (float*)d_out, nullptr, 0, 1, N);
}

// Round 11
// 371.187 us; speedup vs baseline: 1.0422x; 1.0422x over previous
//
#include <hip/hip_runtime.h>

typedef unsigned int uint;
typedef unsigned short ushort;

using bf16x8 = __attribute__((ext_vector_type(8))) short;
using f32x4  = __attribute__((ext_vector_type(4))) float;
using u32x4  = __attribute__((ext_vector_type(4))) uint;

__device__ __forceinline__ float lrelu(float v) { return v > 0.f ? v : 0.01f * v; }
__device__ __forceinline__ float b2f(ushort u) { return __uint_as_float((uint)u << 16); }
__device__ __forceinline__ ushort f2b(float f) {
  uint u = __float_as_uint(f);
  u += 0x7fffu + ((u >> 16) & 1u);   // round-to-nearest-even
  return (ushort)(u >> 16);
}

#define CSR_B 256          // blocks in coarse passes
#define BKT_SHIFT 10       // 1024 dst nodes per bucket
#define MAX_NB 64          // max buckets (N <= 65536)

// y buffers: CHANNEL-CHUNKED 2 chunks x 64 ch: y[chunk][node][64] bf16
// (row = 128 B = one cache line).
// Evidence ledger:
//  R2: nontemporal hints break producer->consumer caching (-21%).
//  R3: LPT perm = 116us atomic contention; imbalance not the issue.
//  R4: 8-wide gather batching (MLP) worth only ~2%.
//  R5: 128B rows / halved requests / broken L2 chunk residency: neutral ->
//      gather tracks BYTES at ~5.9 TB/s (L3-served; kernel-boundary L2
//      invalidation defeats all residency schemes).
//  R6: agg-into-GEMM fusion neutral (lockstep phases, no overlap).
//  R7: cooperative grid.sync overlap -> stale reads (cross-XCD L2). Dead.
//  R8: fp8 y: absmax 131072 = 8x bf16-path error 16384 > threshold 55378.
//      fp8 numerically closed (threshold only 3.4x bf16 baseline error).
//  R9: revert to R5 base; merge prep+chist; fuse readout GEMM into the
//      layer-2 GEMM epilogue via LDS hv tile (bit-identical numerics,
//      -25.6MB traffic, -2 launches).  [R9/R10 = infra failures; 3rd submit]

// ---------------------------------------------------------------------------
// MFMA GEMM: C[N,128] = A[N,K] @ W[K,128] + bias, bf16 in / fp32 acc.
// A = 4 chunked y-buffer pointers (K = 128*buffers), or (F32A=1) fp32 Xf
// with in-register bf16 cast.
// MODE 0: h = lrelu(acc+b); yout = bf16(lrelu(h))           (readin)
// MODE 1: hv = h + acc+b;
//   RDOUT=0: h = hv (if store_h); yout = bf16(act?lrelu(hv):hv)
//   RDOUT=1: bf16(hv) -> LDS tile, then x W2 + bias2 -> h (readout fused;
//            h buffer IS d_out; block reads own rows then overwrites them)
// ---------------------------------------------------------------------------
template <int MODE, int K, int F32A, int RDOUT>
__global__ __launch_bounds__(256) void gemm_mfma(
    const ushort* __restrict__ A0, const ushort* __restrict__ A1,
    const ushort* __restrict__ A2, const ushort* __restrict__ A3,
    const float* __restrict__ Xf,
    const ushort* __restrict__ Wt, const float* __restrict__ bias,
    const ushort* __restrict__ Wt2, const float* __restrict__ bias2,
    float* __restrict__ h, ushort* __restrict__ yout, int do_act, int store_h,
    int N) {
  __shared__ ushort As[64][40];    // [m][k], stride 40 (16B-aligned)
  __shared__ ushort Bs[128][40];   // [n][k]
  __shared__ ushort Hs[RDOUT ? 64 : 1][136];  // fused-readout hv tile
  const int tid = threadIdx.x;
  const int lane = tid & 63;
  const int wave = tid >> 6;
  const int g = lane >> 4;         // k-quad
  const int mr = lane & 15;
  const int wr = wave >> 1;        // row half
  const int wc = wave & 1;         // col half
  const int row0 = blockIdx.x * 64;

  const ushort* Ap[4] = {A0, A1, A2, A3};

  f32x4 acc[2][4];
#pragma unroll
  for (int i = 0; i < 2; i++)
#pragma unroll
    for (int j = 0; j < 4; j++) acc[i][j] = (f32x4){0.f, 0.f, 0.f, 0.f};

#pragma unroll 4
  for (int kc = 0; kc < K; kc += 32) {
    {  // stage A: 64 rows x 32 k (16B of bf16 per thread)
      int m = tid >> 2, q = tid & 3;
      int r = row0 + m;
      if (r >= N) r = N - 1;
      if constexpr (F32A) {
        const float* xp = Xf + (size_t)r * 128 + kc + q * 8;
        f32x4 xa = *(const f32x4*)xp;
        f32x4 xb = *(const f32x4*)(xp + 4);
        union { u32x4 v; ushort u[8]; } o;
        o.u[0] = f2b(xa[0]); o.u[1] = f2b(xa[1]);
        o.u[2] = f2b(xa[2]); o.u[3] = f2b(xa[3]);
        o.u[4] = f2b(xb[0]); o.u[5] = f2b(xb[1]);
        o.u[6] = f2b(xb[2]); o.u[7] = f2b(xb[3]);
        *(u32x4*)&As[m][q * 8] = o.v;
      } else {
        int kg = kc + q * 8;
        // buffer = kg>>7; chunk = (kg>>6)&1 (64-ch chunks)
        const ushort* ap = Ap[kg >> 7] + ((size_t)((kg >> 6) & 1)) * N * 64 +
                           (size_t)r * 64 + (kg & 63);
        *(u32x4*)&As[m][q * 8] = *(const u32x4*)ap;
      }
    }
#pragma unroll
    for (int t = 0; t < 2; t++) {  // stage B: 128 n x 32 k
      int slot = tid + t * 256;
      int n = slot >> 2, q = slot & 3;
      *(u32x4*)&Bs[n][q * 8] = *(const u32x4*)(Wt + (size_t)n * K + kc + q * 8);
    }
    __syncthreads();
    bf16x8 af[2], bf[4];
#pragma unroll
    for (int rt = 0; rt < 2; rt++) af[rt] = *(bf16x8*)&As[wr * 32 + rt * 16 + mr][g * 8];
#pragma unroll
    for (int ct = 0; ct < 4; ct++) bf[ct] = *(bf16x8*)&Bs[wc * 64 + ct * 16 + mr][g * 8];
#pragma unroll
    for (int rt = 0; rt < 2; rt++)
#pragma unroll
      for (int ct = 0; ct < 4; ct++)
        acc[rt][ct] = __builtin_amdgcn_mfma_f32_16x16x32_bf16(af[rt], bf[ct], acc[rt][ct], 0, 0, 0);
    __syncthreads();
  }

  // epilogue: C/D layout col=lane&15, row=(lane>>4)*4+reg
#pragma unroll
  for (int rt = 0; rt < 2; rt++) {
#pragma unroll
    for (int i = 0; i < 4; i++) {
      int R = row0 + wr * 32 + rt * 16 + g * 4 + i;
      if (R >= N) continue;
#pragma unroll
      for (int ct = 0; ct < 4; ct++) {
        int c = wc * 64 + ct * 16 + mr;       // chunk = c>>6, within = c&63
        float v = acc[rt][ct][i] + bias[c];
        size_t o = (size_t)R * 128 + c;
        if (MODE == 0) {
          float hv = lrelu(v);
          h[o] = hv;
          size_t oy = (size_t)(c >> 6) * N * 64 + (size_t)R * 64 + (c & 63);
          yout[oy] = f2b(lrelu(hv));
        } else {
          float hv = h[o] + v;
          if constexpr (RDOUT) {
            Hs[wr * 32 + rt * 16 + g * 4 + i][c] = f2b(hv);
          } else {
            if (store_h) h[o] = hv;
            if (yout) {
              size_t oy = (size_t)(c >> 6) * N * 64 + (size_t)R * 64 + (c & 63);
              yout[oy] = f2b(do_act ? lrelu(hv) : hv);
            }
          }
        }
      }
    }
  }

  if constexpr (RDOUT) {
    // mini-GEMM: d_out[64x128] = Hs(bf16 hv) @ Wt2[128][128] + bias2.
    // All h reads above completed before this sync; writes below hit only
    // this block's own rows.
    __syncthreads();
    f32x4 acc2[2][4];
#pragma unroll
    for (int i = 0; i < 2; i++)
#pragma unroll
      for (int j = 0; j < 4; j++) acc2[i][j] = (f32x4){0.f, 0.f, 0.f, 0.f};
#pragma unroll 4
    for (int kc = 0; kc < 128; kc += 32) {
#pragma unroll
      for (int t = 0; t < 2; t++) {  // stage B from Wt2
        int slot = tid + t * 256;
        int n = slot >> 2, q = slot & 3;
        *(u32x4*)&Bs[n][q * 8] = *(const u32x4*)(Wt2 + (size_t)n * 128 + kc + q * 8);
      }
      __syncthreads();
      bf16x8 af[2], bf[4];
#pragma unroll
      for (int rt = 0; rt < 2; rt++)
        af[rt] = *(bf16x8*)&Hs[wr * 32 + rt * 16 + mr][kc + g * 8];
#pragma unroll
      for (int ct = 0; ct < 4; ct++)
        bf[ct] = *(bf16x8*)&Bs[wc * 64 + ct * 16 + mr][g * 8];
#pragma unroll
      for (int rt = 0; rt < 2; rt++)
#pragma unroll
        for (int ct = 0; ct < 4; ct++)
          acc2[rt][ct] = __builtin_amdgcn_mfma_f32_16x16x32_bf16(af[rt], bf[ct], acc2[rt][ct], 0, 0, 0);
      __syncthreads();
    }
#pragma unroll
    for (int rt = 0; rt < 2; rt++) {
#pragma unroll
      for (int i = 0; i < 4; i++) {
        int R = row0 + wr * 32 + rt * 16 + g * 4 + i;
        if (R >= N) continue;
#pragma unroll
        for (int ct = 0; ct < 4; ct++) {
          int c = wc * 64 + ct * 16 + mr;
          h[(size_t)R * 128 + c] = acc2[rt][ct][i] + bias2[c];
        }
      }
    }
  }
}

// ---------------- bf16 aggregation, chunked: out[c][n] = sum y[c][src] -------
// chunk = blockIdx&1. 8 lanes x 16B (8 bf16) per node -> one 128 B line per
// lane-octet. 32 nodes per block. 8-wide gather batches.
__global__ __launch_bounds__(256) void agg_bf16(const ushort* __restrict__ yin,
                                                ushort* __restrict__ yout,
                                                const int* __restrict__ rowp,
                                                const ushort* __restrict__ esrc, int N) {
  int t = threadIdx.x;
  int chunk = blockIdx.x & 1;
  int node = (blockIdx.x >> 1) * 32 + (t >> 3);
  if (node >= N) return;
  int lane = t & 7;
  const ushort* yb = yin + (size_t)chunk * N * 64 + lane * 8;
  int beg = rowp[node], end = rowp[node + 1];
  float s[8] = {0.f, 0.f, 0.f, 0.f, 0.f, 0.f, 0.f, 0.f};
  int j = beg;
  for (; j + 8 <= end; j += 8) {
    int is[8];
#pragma unroll
    for (int e = 0; e < 8; e++) is[e] = esrc[j + e];
    u32x4 w[8];
#pragma unroll
    for (int e = 0; e < 8; e++) w[e] = *(const u32x4*)(yb + (size_t)is[e] * 64);
#pragma unroll
    for (int e = 0; e < 8; e++) {
      union { u32x4 v; ushort u[8]; } q;
      q.v = w[e];
#pragma unroll
      for (int c = 0; c < 8; c++) s[c] += b2f(q.u[c]);
    }
  }
  if (j + 4 <= end) {
    int is[4];
#pragma unroll
    for (int e = 0; e < 4; e++) is[e] = esrc[j + e];
    u32x4 w[4];
#pragma unroll
    for (int e = 0; e < 4; e++) w[e] = *(const u32x4*)(yb + (size_t)is[e] * 64);
#pragma unroll
    for (int e = 0; e < 4; e++) {
      union { u32x4 v; ushort u[8]; } q;
      q.v = w[e];
#pragma unroll
      for (int c = 0; c < 8; c++) s[c] += b2f(q.u[c]);
    }
    j += 4;
  }
  for (; j < end; j++) {
    int sn = esrc[j];
    union { u32x4 v; ushort u[8]; } w;
    w.v = *(const u32x4*)(yb + (size_t)sn * 64);
#pragma unroll
    for (int e = 0; e < 8; e++) s[e] += b2f(w.u[e]);
  }
  union { u32x4 v; ushort u[8]; } o;
#pragma unroll
  for (int e = 0; e < 8; e++) o.u[e] = f2b(s[e]);
  *(u32x4*)(yout + (size_t)chunk * N * 64 + (size_t)node * 64 + lane * 8) = o.v;
}

// ---------------- merged weight prep + dst histogram -------------------------
__global__ __launch_bounds__(256) void prep_chist_k(
    const int* __restrict__ dst, int* __restrict__ H, int E, int NB,
    const float* __restrict__ w_in, const float* __restrict__ w_out,
    const float* __restrict__ taps_w, const float* __restrict__ taps_b,
    ushort* __restrict__ Wt_in, ushort* __restrict__ Wt_out,
    ushort* __restrict__ Wt_l0, ushort* __restrict__ Wt_l1,
    float* __restrict__ bsum) {
  if (blockIdx.x < CSR_B) {
    __shared__ int hh[MAX_NB];
    if (threadIdx.x < NB) hh[threadIdx.x] = 0;
    __syncthreads();
    int chunk = (E + CSR_B - 1) / CSR_B;
    int beg = blockIdx.x * chunk, end = min(E, beg + chunk);
    for (int e = beg + threadIdx.x; e < end; e += 256)
      atomicAdd(&hh[dst[e] >> BKT_SHIFT], 1);
    __syncthreads();
    if (threadIdx.x < NB) H[threadIdx.x * CSR_B + blockIdx.x] = hh[threadIdx.x];
    return;
  }
  int gid = (blockIdx.x - CSR_B) * 256 + threadIdx.x;
  if (gid < 16384) {
    int n = gid >> 7, k = gid & 127;
    Wt_in[gid] = f2b(w_in[k * 128 + n]);
  } else if (gid < 32768) {
    int i = gid - 16384;
    int n = i >> 7, k = i & 127;
    Wt_out[i] = f2b(w_out[k * 128 + n]);
  } else if (gid < 98304) {
    int i = gid - 32768;
    int n = i >> 9, k = i & 511;
    Wt_l0[i] = f2b(taps_w[(size_t)k * 128 + n]);
  } else if (gid < 163840) {
    int i = gid - 98304;
    int n = i >> 9, k = i & 511;
    Wt_l1[i] = f2b(taps_w[(size_t)(512 + k) * 128 + n]);
  } else if (gid < 164096) {
    int i = gid - 163840;
    int l = i >> 7, n = i & 127;
    float s = 0.f;
    for (int k = 0; k < 4; k++) s += taps_b[l * 512 + k * 128 + n];
    bsum[i] = s;
  }
}

// ---------------- CSR build: scan / scatter / bucket sort --------------------
__global__ __launch_bounds__(256) void cscan_k(int* __restrict__ H, int M) {
  __shared__ int sm[256];
  int per = (M + 255) / 256;
  int b0 = threadIdx.x * per;
  int hi = min(M, b0 + per);
  int sum = 0;
  for (int i = b0; i < hi; i++) sum += H[i];
  sm[threadIdx.x] = sum;
  __syncthreads();
  int x = sum;
  for (int off = 1; off < 256; off <<= 1) {
    int tt = (threadIdx.x >= off) ? sm[threadIdx.x - off] : 0;
    __syncthreads();
    x += tt;
    sm[threadIdx.x] = x;
    __syncthreads();
  }
  int run = x - sum;  // exclusive
  for (int i = b0; i < hi; i++) {
    int v = H[i];
    H[i] = run;
    run += v;
  }
}

__global__ __launch_bounds__(256) void cscatter_k(const int* __restrict__ src,
                                                  const int* __restrict__ dst,
                                                  const int* __restrict__ H,
                                                  uint* __restrict__ packed,
                                                  int E, int NB) {
  __shared__ int cur[MAX_NB];
  int chunk = (E + gridDim.x - 1) / gridDim.x;
  int beg = blockIdx.x * chunk, end = min(E, beg + chunk);
  if (threadIdx.x < NB) cur[threadIdx.x] = H[threadIdx.x * gridDim.x + blockIdx.x];
  __syncthreads();
  for (int e = beg + threadIdx.x; e < end; e += 256) {
    int d = dst[e];
    int pos = atomicAdd(&cur[d >> BKT_SHIFT], 1);
    packed[pos] = ((uint)d << 16) | (uint)src[e];
  }
}

__global__ __launch_bounds__(256) void fsort_k(const uint* __restrict__ packed,
                                               const int* __restrict__ H,
                                               ushort* __restrict__ esrc,
                                               int* __restrict__ rowp,
                                               int N, int E, int NB) {
  __shared__ int hist[1 << BKT_SHIFT];
  __shared__ int cur[1 << BKT_SHIFT];
  __shared__ int sm[256];
  const int bkt = blockIdx.x;
  const int base = bkt << BKT_SHIFT;
  const int nb_nodes = min(1 << BKT_SHIFT, N - base);
  const int start = H[bkt * CSR_B];
  const int end = (bkt == NB - 1) ? E : H[(bkt + 1) * CSR_B];

  for (int i = threadIdx.x; i < (1 << BKT_SHIFT); i += 256) hist[i] = 0;
  __syncthreads();
  for (int e = start + threadIdx.x; e < end; e += 256)
    atomicAdd(&hist[(packed[e] >> 16) - base], 1);
  __syncthreads();

  int t4 = threadIdx.x * 4;
  int l0 = hist[t4], l1 = hist[t4 + 1], l2 = hist[t4 + 2], l3 = hist[t4 + 3];
  int ssum = l0 + l1 + l2 + l3;
  sm[threadIdx.x] = ssum;
  __syncthreads();
  int x = ssum;
  for (int off = 1; off < 256; off <<= 1) {
    int tt = (threadIdx.x >= off) ? sm[threadIdx.x - off] : 0;
    __syncthreads();
    x += tt;
    sm[threadIdx.x] = x;
    __syncthreads();
  }
  int c0 = start + x - ssum;
  int c1 = c0 + l0, c2 = c1 + l1, c3 = c2 + l2;
  cur[t4] = c0; cur[t4 + 1] = c1; cur[t4 + 2] = c2; cur[t4 + 3] = c3;
  if (t4 + 0 < nb_nodes) rowp[base + t4 + 0] = c0;
  if (t4 + 1 < nb_nodes) rowp[base + t4 + 1] = c1;
  if (t4 + 2 < nb_nodes) rowp[base + t4 + 2] = c2;
  if (t4 + 3 < nb_nodes) rowp[base + t4 + 3] = c3;
  __syncthreads();

  for (int e = start + threadIdx.x; e < end; e += 256) {
    uint p = packed[e];
    int pos = atomicAdd(&cur[(p >> 16) - base], 1);
    esrc[pos] = (ushort)(p & 0xffffu);
  }
  if (bkt == 0 && threadIdx.x == 0) rowp[N] = E;
}

// ---------------------------------------------------------------------------
extern "C" void kernel_launch(void* const* d_in, const int* in_sizes, int n_in,
                              void* d_out, int out_size, void* d_ws, size_t ws_size,
                              hipStream_t stream) {
  const float* x      = (const float*)d_in[0];
  const int*   ei     = (const int*)d_in[1];
  const float* w_in   = (const float*)d_in[2];
  const float* b_in   = (const float*)d_in[3];
  const float* taps_w = (const float*)d_in[4];
  const float* taps_b = (const float*)d_in[5];
  const float* w_out  = (const float*)d_in[6];
  const float* b_out  = (const float*)d_in[7];

  const int N = in_sizes[0] / 128;
  const int E = in_sizes[1] / 2;
  const int* src = ei;
  const int* dst = ei + E;
  const int NB = (N + (1 << BKT_SHIFT) - 1) >> BKT_SHIFT;

  // h (fp32) lives in d_out; the fused readout overwrites it in-place.
  float* h = (float*)d_out;

  // workspace (~57 MB)
  const size_t yelem = (size_t)N * 128;
  ushort* y0 = (ushort*)d_ws;
  ushort* y1 = y0 + yelem;
  ushort* y2 = y1 + yelem;
  ushort* y3 = y2 + yelem;
  ushort* Wt_in  = y3 + yelem;             // 128*128
  ushort* Wt_out = Wt_in + 128 * 128;      // 128*128
  ushort* Wt_l0  = Wt_out + 128 * 128;     // 128*512
  ushort* Wt_l1  = Wt_l0 + 128 * 512;      // 128*512
  float*  bsum   = (float*)(Wt_l1 + 128 * 512);   // 256
  int*    rowp   = (int*)(bsum + 256);     // N+1
  int*    H      = rowp + (N + 1);         // NB*CSR_B
  uint*   packed = (uint*)(H + MAX_NB * CSR_B);   // E
  ushort* esrc   = (ushort*)(packed + E);  // E

  const int gemmB = (N + 63) / 64;
  const int aggB  = ((N + 31) / 32) * 2;   // node-blocks x 2 chunks

  // ---- weight prep || dst histogram (one launch) ----
  prep_chist_k<<<CSR_B + 641, 256, 0, stream>>>(dst, H, E, NB,
      w_in, w_out, taps_w, taps_b, Wt_in, Wt_out, Wt_l0, Wt_l1, bsum);
  cscan_k<<<1, 256, 0, stream>>>(H, NB * CSR_B);
  cscatter_k<<<CSR_B, 256, 0, stream>>>(src, dst, H, packed, E, NB);
  fsort_k<<<NB, 256, 0, stream>>>(packed, H, esrc, rowp, N, E, NB);

  // ---- readin: h = lrelu(x@Win+b); y0 = bf16(lrelu(h)); x cast fused ----
  gemm_mfma<0, 128, 1, 0><<<gemmB, 256, 0, stream>>>(
      nullptr, nullptr, nullptr, nullptr, x, Wt_in, b_in, nullptr, nullptr,
      h, y0, 0, 1, N);

  // ---- layer 0: 3 aggs + GEMM (writes h and y0 for layer 1) ----
  agg_bf16<<<aggB, 256, 0, stream>>>(y0, y1, rowp, esrc, N);
  agg_bf16<<<aggB, 256, 0, stream>>>(y1, y2, rowp, esrc, N);
  agg_bf16<<<aggB, 256, 0, stream>>>(y2, y3, rowp, esrc, N);
  gemm_mfma<1, 512, 0, 0><<<gemmB, 256, 0, stream>>>(
      y0, y1, y2, y3, nullptr, Wt_l0, bsum, nullptr, nullptr,
      h, y0, 1, 1, N);

  // ---- layer 1: 3 aggs + GEMM with FUSED READOUT (writes d_out in place) ----
  agg_bf16<<<aggB, 256, 0, stream>>>(y0, y1, rowp, esrc, N);
  agg_bf16<<<aggB, 256, 0, stream>>>(y1, y2, rowp, esrc, N);
  agg_bf16<<<aggB, 256, 0, stream>>>(y2, y3, rowp, esrc, N);
  gemm_mfma<1, 512, 0, 1><<<gemmB, 256, 0, stream>>>(
      y0, y1, y2, y3, nullptr, Wt_l1, bsum + 128, Wt_out, b_out,
      h, nullptr, 0, 0, N);
}